// Round 3
// baseline (853.443 us; speedup 1.0000x reference)
//
#include <hip/hip_runtime.h>
#include <hip/hip_bf16.h>
#include <math.h>

typedef __bf16 bf16_t;
typedef __bf16 bf16x8 __attribute__((ext_vector_type(8)));
typedef float f32x4 __attribute__((ext_vector_type(4)));

#define QEPS 1e-5

__device__ __forceinline__ void gload_lds16(const void* g, void* l) {
  __builtin_amdgcn_global_load_lds((const __attribute__((address_space(1))) void*)g,
                                   (__attribute__((address_space(3))) void*)l, 16, 0, 0);
}

// exact GELU via A&S 7.1.26 erf (|err| <= 1.5e-7), branchless
__device__ __forceinline__ float gelu_exact(float x) {
  float a = x * 0.7071067811865476f;
  float s = fabsf(a);
  float t = __builtin_amdgcn_rcpf(__builtin_fmaf(0.3275911f, s, 1.0f));
  float p = __builtin_fmaf(1.061405429f, t, -1.453152027f);
  p = __builtin_fmaf(p, t, 1.421413741f);
  p = __builtin_fmaf(p, t, -0.284496736f);
  p = __builtin_fmaf(p, t, 0.254829592f);
  p = p * t;
  float e = __expf(-s * s);
  float er = copysignf(__builtin_fmaf(-p, e, 1.0f), a);
  return 0.5f * x * (1.0f + er);
}

// ---- P1: per-block fp64 partial sums of |w| ----
__global__ void reduce_part_kernel(const float* __restrict__ w1, const float* __restrict__ w2,
                                   int n, double* __restrict__ part) {
  const bool second = blockIdx.x >= 256;
  const float* __restrict__ w = second ? w2 : w1;
  const int b = second ? blockIdx.x - 256 : blockIdx.x;
  double s = 0.0;
  const int stride = 256 * 256 * 4;
  for (int i = (b * 256 + threadIdx.x) * 4; i < n; i += stride) {
    float4 v = *(const float4*)(w + i);
    s += (double)fabsf(v.x) + (double)fabsf(v.y) + (double)fabsf(v.z) + (double)fabsf(v.w);
  }
  for (int off = 32; off > 0; off >>= 1)
    s += __shfl_down(s, off, 64);
  __shared__ double ls[4];
  int lane = threadIdx.x & 63, wv = threadIdx.x >> 6;
  if (lane == 0) ls[wv] = s;
  __syncthreads();
  if (threadIdx.x == 0) part[blockIdx.x] = ls[0] + ls[1] + ls[2] + ls[3];
}

// ---- P2: quantize w1,w2 (XOR-swizzled tiles, they go through global_load_lds)
//       + cast/pad x (UNSWIZZLED tiles, read direct global->VGPR by GEMM) ----
// Tile = 128 rows x 64 k-cols bf16 (8192 elems, 16 KB).
// Weights: chunk (r*8 + slot) holds k-chunk (slot ^ (r&7))  [proven 0-conflict]
// x:       chunk (r*8 + slot) holds k-chunk slot             [plain]
__global__ void prep_kernel(const float* __restrict__ w1, const float* __restrict__ w2,
                            const float* __restrict__ x, const double* __restrict__ part,
                            double* __restrict__ gammas, bf16_t* __restrict__ q1,
                            bf16_t* __restrict__ q2, bf16_t* __restrict__ xb) {
  const int tid = threadIdx.x;
  const int b = blockIdx.x;
  if (b < 2304) {                      // weight quantize: 1152 blocks each
    const bool second = b >= 1152;
    double p = part[(second ? 256 : 0) + tid];
    for (int off = 32; off > 0; off >>= 1)
      p += __shfl_down(p, off, 64);
    __shared__ double red[4];
    if ((tid & 63) == 0) red[tid >> 6] = p;
    __syncthreads();
    const double g = (red[0] + red[1] + red[2] + red[3]) / 2359296.0 + QEPS;
    if (tid == 0 && (b == 0 || b == 1152)) gammas[second ? 1 : 0] = g;
    const double rg = 1.0 / g;
    const int gchunk = (second ? b - 1152 : b) * 256 + tid;   // < 294912
    const int tile = gchunk >> 10, cidx = gchunk & 1023;
    const int r = cidx >> 3, slot = cidx & 7, kc = slot ^ (r & 7);
    int row, col, C;
    const float* __restrict__ W;
    if (second) { C = 3072; W = w2; row = (tile / 48) * 128 + r; col = (tile % 48) * 64 + kc * 8; }
    else        { C = 768;  W = w1; row = (tile / 12) * 128 + r; col = (tile % 12) * 64 + kc * 8; }
    const float4 v0 = *(const float4*)(W + (size_t)row * C + col);
    const float4 v1 = *(const float4*)(W + (size_t)row * C + col + 4);
    bf16x8 o;
    o[0] = (bf16_t)(float)fmin(1.0, fmax(-1.0, rint((double)v0.x * rg)));
    o[1] = (bf16_t)(float)fmin(1.0, fmax(-1.0, rint((double)v0.y * rg)));
    o[2] = (bf16_t)(float)fmin(1.0, fmax(-1.0, rint((double)v0.z * rg)));
    o[3] = (bf16_t)(float)fmin(1.0, fmax(-1.0, rint((double)v0.w * rg)));
    o[4] = (bf16_t)(float)fmin(1.0, fmax(-1.0, rint((double)v1.x * rg)));
    o[5] = (bf16_t)(float)fmin(1.0, fmax(-1.0, rint((double)v1.y * rg)));
    o[6] = (bf16_t)(float)fmin(1.0, fmax(-1.0, rint((double)v1.z * rg)));
    o[7] = (bf16_t)(float)fmin(1.0, fmax(-1.0, rint((double)v1.w * rg)));
    *(bf16x8*)((second ? q2 : q1) + (size_t)gchunk * 8) = o;
  } else {                             // x cast/pad: 4800 blocks (12800 rows), UNSWIZZLED
    const int gchunk = (b - 2304) * 256 + tid;                // < 1228800
    const int tile = gchunk >> 10, cidx = gchunk & 1023;
    const int r = cidx >> 3, slot = cidx & 7;
    const int row = (tile / 12) * 128 + r;
    const int col = (tile % 12) * 64 + slot * 8;
    bf16x8 o;
    if (row < 12608) {
      const float4 v0 = *(const float4*)(x + (size_t)row * 768 + col);
      const float4 v1 = *(const float4*)(x + (size_t)row * 768 + col + 4);
      o[0] = (bf16_t)v0.x; o[1] = (bf16_t)v0.y; o[2] = (bf16_t)v0.z; o[3] = (bf16_t)v0.w;
      o[4] = (bf16_t)v1.x; o[5] = (bf16_t)v1.y; o[6] = (bf16_t)v1.z; o[7] = (bf16_t)v1.w;
    } else {
      o = bf16x8{};
    }
    *(bf16x8*)(xb + (size_t)gchunk * 8) = o;
  }
}

// ---- GEMM: 128x128 block, BK=64, 256 threads (2x2 waves, 64x64/wave).
// A-operand: DIRECT global->VGPR (unswizzled tiles; coalesced-equivalent:
//   16 fully-consumed cachelines/instr; 2nd wave-col hits L1). Reg-double-
//   buffered awA/awB (static indexing, manual 2x unroll). Compiler emits
//   COUNTED vmcnt for these reg deps -> A loads stay in flight across
//   barriers (T4 mechanism without asm fragility).
// B-operand: via LDS (4x reuse), 2x16KB STATIC dbuf. Only B's 4 stage-loads
//   must drain at the barrier: issue order pinned (stage -> sched_barrier(0)
//   -> A-loads), then s_waitcnt vmcnt(8) leaves the 8 A-loads in flight.
// LDS traffic halves vs round-2 (48 KB vs 96 KB per block-K-tile); 32 KB
// static LDS + launch_bounds(256,4) -> 4 blocks/CU -> MFMA-pipe-bound.
// EPI==0: hb tiles (blocked UNSWIZZLED bf16) = gelu(gamma*acc+bias), via LDS
// EPI==1: fp32 row-major out (stride aux), rows < Mvalid
template <int EPI>
__global__ __launch_bounds__(256, 4)
void gemm_ar(const bf16_t* __restrict__ A, const bf16_t* __restrict__ B,
             const float* __restrict__ bias, const double* __restrict__ gptr,
             void* __restrict__ Cout, int nkt, int gx, int Mvalid, int aux) {
  __shared__ bf16_t sm[2][8192];       // B double buffer, 32 KB total

  // bijective XCD-chunked tile id (grid % 8 == 0 for both launches)
  const int G = gridDim.x;
  const int f = blockIdx.x;
  const int xcd = f & 7;
  const int idx = f >> 3;
  const int q8 = G >> 3, r8 = G & 7;
  const int t = xcd * q8 + (xcd < r8 ? xcd : r8) + idx;
  const int bx = t % gx;
  const int by = t / gx;

  const int tid = threadIdx.x;
  const int lane = tid & 63;
  const int wave = tid >> 6;
  const int row16 = lane & 15;
  const int quad = lane >> 4;
  const int wr = (wave >> 1) * 64;
  const int wc = (wave & 1) * 64;

  const bf16_t* const Ab = A + (size_t)by * nkt * 8192;
  const bf16_t* const Bb = B + (size_t)bx * nkt * 8192;

  // A per-lane element offset within a tile (unswizzled): row*64 + quad*8
  const int abase = (wr + row16) * 64 + quad * 8;     // +i*1024 rows, +32 ksub1
  // B swizzled LDS read offsets (proven conflict-free)
  const int sw0 = (quad ^ (row16 & 7)) * 8;
  const int boffA = (wc + row16) * 64 + sw0;          // ksub0, +j*1024
  const int boffB = (wc + row16) * 64 + (sw0 ^ 32);   // ksub1

  f32x4 acc[4][4] = {};
  bf16x8 awA[8], awB[8], bw[8];

#define LOADA_(dst, tt) do { \
    const bf16_t* ap_ = Ab + (size_t)(tt) * 8192 + abase; \
    _Pragma("unroll") for (int i_ = 0; i_ < 4; i_++) { \
      dst[2 * i_]     = *(const bf16x8*)(ap_ + i_ * 1024); \
      dst[2 * i_ + 1] = *(const bf16x8*)(ap_ + i_ * 1024 + 32); } } while (0)
#define STAGEB_(tt, bufv) do { \
    const bf16_t* sp_ = Bb + (size_t)(tt) * 8192; \
    bf16_t* dp_ = sm[bufv]; \
    _Pragma("unroll") for (int l_ = 0; l_ < 4; l_++) \
      gload_lds16(sp_ + l_ * 2048 + tid * 8, dp_ + l_ * 2048 + wave * 512); } while (0)
#define LOADB_(bufv) do { \
    const bf16_t* b0_ = sm[bufv] + boffA; \
    const bf16_t* b1_ = sm[bufv] + boffB; \
    _Pragma("unroll") for (int j_ = 0; j_ < 4; j_++) { \
      bw[2 * j_]     = *(const bf16x8*)(b0_ + j_ * 1024); \
      bw[2 * j_ + 1] = *(const bf16x8*)(b1_ + j_ * 1024); } } while (0)
#define MFMAALL_(awc) do { \
    _Pragma("unroll") for (int i_ = 0; i_ < 4; i_++) \
    _Pragma("unroll") for (int j_ = 0; j_ < 4; j_++) { \
      acc[i_][j_] = __builtin_amdgcn_mfma_f32_16x16x32_bf16(awc[2*i_],   bw[2*j_],   acc[i_][j_], 0, 0, 0); \
      acc[i_][j_] = __builtin_amdgcn_mfma_f32_16x16x32_bf16(awc[2*i_+1], bw[2*j_+1], acc[i_][j_], 0, 0, 0); } } while (0)
// Body t: reads B from buf (cur), A from awc; prefetches B(t+1)->buf^1 and
// A(t+1)->awn. Ledger at the wait: outstanding = stage(t+1)[4, oldest] +
// awn[8] -> vmcnt(8) drains exactly the stage; awn rides across the barrier.
#define BODY_(tt, curb, awc, awn) do { \
    if ((tt) + 1 < nkt) STAGEB_((tt) + 1, (curb) ^ 1); \
    __builtin_amdgcn_sched_barrier(0); \
    if ((tt) + 1 < nkt) LOADA_(awn, (tt) + 1); \
    LOADB_(curb); \
    MFMAALL_(awc); \
    if ((tt) + 1 < nkt) { \
      asm volatile("s_waitcnt vmcnt(8)" ::: "memory"); \
      __builtin_amdgcn_s_barrier(); } } while (0)

  // prologue: stage B(0) -> buf0, load A(0) -> awA; drain only the stage
  STAGEB_(0, 0);
  __builtin_amdgcn_sched_barrier(0);
  LOADA_(awA, 0);
  asm volatile("s_waitcnt vmcnt(8)" ::: "memory");
  __builtin_amdgcn_s_barrier();

  for (int T = 0; T < nkt; T += 2) {   // nkt even (12 / 48)
    BODY_(T, 0, awA, awB);
    BODY_(T + 1, 1, awB, awA);
  }

  const float gamma = (float)gptr[0];
  float bv[4];
#pragma unroll
  for (int j = 0; j < 4; j++) bv[j] = bias[bx * 128 + wc + j * 16 + row16];

  if constexpr (EPI == 0) {
    // h = gelu(gamma*acc + bias) -> blocked UNSWIZZLED 128x64 tiles.
    // LDS bounce in 2 half-passes (rows {0-31,64-95} then {32-63,96-127})
    // since only 32 KB static LDS is available. SEW=136 keeps b128 aligned.
    constexpr int SEW = 136;
    bf16_t* sE = &sm[0][0];
    bf16_t* hbp = (bf16_t*)Cout;       // aux = k-tiles of h (48)
    __syncthreads();                   // main-loop LDS reads fully done
#pragma unroll
    for (int h = 0; h < 2; h++) {
#pragma unroll
      for (int u = 0; u < 2; u++) {
        const int i = 2 * h + u;
        const int rb = wr + i * 16 + quad * 4;
#pragma unroll
        for (int j = 0; j < 4; j++) {
          const int col = wc + j * 16 + row16;
#pragma unroll
          for (int r = 0; r < 4; r++) {
            const int row = rb + r;
            const int e = (row & 31) + ((row & 64) >> 1);
            sE[e * SEW + col] = (bf16_t)gelu_exact(__builtin_fmaf(gamma, acc[i][j][r], bv[j]));
          }
        }
      }
      __syncthreads();
#pragma unroll
      for (int n = 0; n < 4; n++) {
        const int g = n * 256 + tid;
        const int e = g >> 4, ch = g & 15;
        const int grow = (e & 31) + ((e & 32) << 1) + 32 * h;
        const size_t off = ((size_t)by * aux + bx * 2 + (ch >> 3)) * 8192 + (grow * 8 + (ch & 7)) * 8;
        *(bf16x8*)(hbp + off) = *(const bf16x8*)(sE + e * SEW + ch * 8);
      }
      __syncthreads();
    }
  } else {
    float* outp = (float*)Cout;        // aux = row stride (=768)
#pragma unroll
    for (int j = 0; j < 4; j++) {
      const int col = bx * 128 + wc + j * 16 + row16;
#pragma unroll
      for (int i = 0; i < 4; i++) {
        const int rb = by * 128 + wr + i * 16 + quad * 4;
#pragma unroll
        for (int r = 0; r < 4; r++)
          if (rb + r < Mvalid)
            outp[(size_t)(rb + r) * aux + col] = __builtin_fmaf(gamma, acc[i][j][r], bv[j]);
      }
    }
  }
#undef LOADA_
#undef STAGEB_
#undef LOADB_
#undef MFMAALL_
#undef BODY_
}

extern "C" void kernel_launch(void* const* d_in, const int* in_sizes, int n_in,
                              void* d_out, int out_size, void* d_ws, size_t ws_size,
                              hipStream_t stream) {
  const float* x  = (const float*)d_in[0];
  const float* w1 = (const float*)d_in[1];
  const float* b1 = (const float*)d_in[2];
  const float* w2 = (const float*)d_in[3];
  const float* b2 = (const float*)d_in[4];
  float* out = (float*)d_out;

  const int M = 64 * 197;      // 12608
  const int Mpad = 12800;      // 100 row-tiles of 128
  const int D = 768, H = 3072;
  const int nW = H * D;        // 2359296

  char* ws = (char*)d_ws;
  double* part = (double*)ws;                      // [512] @ ws[0,4096)
  double* gammas = (double*)(ws + 4096);           // [2] own cacheline
  bf16_t* xb  = (bf16_t*)(ws + 4096 + 256);        // 100x12 tiles of 128x64
  bf16_t* w1q = xb + (size_t)Mpad * D;             // 24x12 tiles
  bf16_t* w2q = w1q + (size_t)H * D;               // 6x48 tiles
  bf16_t* hb  = w2q + (size_t)D * H;               // 100x48 tiles

  reduce_part_kernel<<<512, 256, 0, stream>>>(w1, w2, nW, part);
  prep_kernel<<<2304 + 4800, 256, 0, stream>>>(w1, w2, x, part, gammas, w1q, w2q, xb);

  // GEMM1: 128x128 blocks, grid 100*24=2400; A=xb(nkt=12), B=w1q -> hb
  gemm_ar<0><<<100 * 24, 256, 0, stream>>>(xb, w1q, b1, gammas + 0, hb, 12, 24, M, H / 64);
  // GEMM2: 128x128 blocks, grid 100*6=600; A=hb(nkt=48), B=w2q -> fp32 out
  gemm_ar<1><<<100 * 6, 256, 0, stream>>>(hb, w2q, b2, gammas + 1, out, 48, 6, M, D);
}

// Round 4
// 430.004 us; speedup vs baseline: 1.9847x; 1.9847x over previous
//
#include <hip/hip_runtime.h>
#include <hip/hip_bf16.h>
#include <math.h>

typedef __bf16 bf16_t;
typedef __bf16 bf16x8 __attribute__((ext_vector_type(8)));
typedef float f32x4 __attribute__((ext_vector_type(4)));

#define QEPS 1e-5

__device__ __forceinline__ void gload_lds16(const void* g, void* l) {
  __builtin_amdgcn_global_load_lds((const __attribute__((address_space(1))) void*)g,
                                   (__attribute__((address_space(3))) void*)l, 16, 0, 0);
}

// exact GELU via A&S 7.1.26 erf (|err| <= 1.5e-7), branchless
__device__ __forceinline__ float gelu_exact(float x) {
  float a = x * 0.7071067811865476f;
  float s = fabsf(a);
  float t = __builtin_amdgcn_rcpf(__builtin_fmaf(0.3275911f, s, 1.0f));
  float p = __builtin_fmaf(1.061405429f, t, -1.453152027f);
  p = __builtin_fmaf(p, t, 1.421413741f);
  p = __builtin_fmaf(p, t, -0.284496736f);
  p = __builtin_fmaf(p, t, 0.254829592f);
  p = p * t;
  float e = __expf(-s * s);
  float er = copysignf(__builtin_fmaf(-p, e, 1.0f), a);
  return 0.5f * x * (1.0f + er);
}

// ---- P1: per-block fp64 partial sums of |w| ----
__global__ void reduce_part_kernel(const float* __restrict__ w1, const float* __restrict__ w2,
                                   int n, double* __restrict__ part) {
  const bool second = blockIdx.x >= 256;
  const float* __restrict__ w = second ? w2 : w1;
  const int b = second ? blockIdx.x - 256 : blockIdx.x;
  double s = 0.0;
  const int stride = 256 * 256 * 4;
  for (int i = (b * 256 + threadIdx.x) * 4; i < n; i += stride) {
    float4 v = *(const float4*)(w + i);
    s += (double)fabsf(v.x) + (double)fabsf(v.y) + (double)fabsf(v.z) + (double)fabsf(v.w);
  }
  for (int off = 32; off > 0; off >>= 1)
    s += __shfl_down(s, off, 64);
  __shared__ double ls[4];
  int lane = threadIdx.x & 63, wv = threadIdx.x >> 6;
  if (lane == 0) ls[wv] = s;
  __syncthreads();
  if (threadIdx.x == 0) part[blockIdx.x] = ls[0] + ls[1] + ls[2] + ls[3];
}

// ---- P2: quantize w1,w2 (XOR-swizzled tiles, they go through global_load_lds)
//       + cast/pad x (UNSWIZZLED tiles, read direct global->VGPR by GEMM) ----
// Tile = 128 rows x 64 k-cols bf16 (8192 elems, 16 KB).
// Weights: chunk (r*8 + slot) holds k-chunk (slot ^ (r&7))  [proven 0-conflict]
// x:       chunk (r*8 + slot) holds k-chunk slot             [plain]
__global__ void prep_kernel(const float* __restrict__ w1, const float* __restrict__ w2,
                            const float* __restrict__ x, const double* __restrict__ part,
                            double* __restrict__ gammas, bf16_t* __restrict__ q1,
                            bf16_t* __restrict__ q2, bf16_t* __restrict__ xb) {
  const int tid = threadIdx.x;
  const int b = blockIdx.x;
  if (b < 2304) {                      // weight quantize: 1152 blocks each
    const bool second = b >= 1152;
    double p = part[(second ? 256 : 0) + tid];
    for (int off = 32; off > 0; off >>= 1)
      p += __shfl_down(p, off, 64);
    __shared__ double red[4];
    if ((tid & 63) == 0) red[tid >> 6] = p;
    __syncthreads();
    const double g = (red[0] + red[1] + red[2] + red[3]) / 2359296.0 + QEPS;
    if (tid == 0 && (b == 0 || b == 1152)) gammas[second ? 1 : 0] = g;
    const double rg = 1.0 / g;
    const int gchunk = (second ? b - 1152 : b) * 256 + tid;   // < 294912
    const int tile = gchunk >> 10, cidx = gchunk & 1023;
    const int r = cidx >> 3, slot = cidx & 7, kc = slot ^ (r & 7);
    int row, col, C;
    const float* __restrict__ W;
    if (second) { C = 3072; W = w2; row = (tile / 48) * 128 + r; col = (tile % 48) * 64 + kc * 8; }
    else        { C = 768;  W = w1; row = (tile / 12) * 128 + r; col = (tile % 12) * 64 + kc * 8; }
    const float4 v0 = *(const float4*)(W + (size_t)row * C + col);
    const float4 v1 = *(const float4*)(W + (size_t)row * C + col + 4);
    bf16x8 o;
    o[0] = (bf16_t)(float)fmin(1.0, fmax(-1.0, rint((double)v0.x * rg)));
    o[1] = (bf16_t)(float)fmin(1.0, fmax(-1.0, rint((double)v0.y * rg)));
    o[2] = (bf16_t)(float)fmin(1.0, fmax(-1.0, rint((double)v0.z * rg)));
    o[3] = (bf16_t)(float)fmin(1.0, fmax(-1.0, rint((double)v0.w * rg)));
    o[4] = (bf16_t)(float)fmin(1.0, fmax(-1.0, rint((double)v1.x * rg)));
    o[5] = (bf16_t)(float)fmin(1.0, fmax(-1.0, rint((double)v1.y * rg)));
    o[6] = (bf16_t)(float)fmin(1.0, fmax(-1.0, rint((double)v1.z * rg)));
    o[7] = (bf16_t)(float)fmin(1.0, fmax(-1.0, rint((double)v1.w * rg)));
    *(bf16x8*)((second ? q2 : q1) + (size_t)gchunk * 8) = o;
  } else {                             // x cast/pad: 4800 blocks (12800 rows), UNSWIZZLED
    const int gchunk = (b - 2304) * 256 + tid;                // < 1228800
    const int tile = gchunk >> 10, cidx = gchunk & 1023;
    const int r = cidx >> 3, slot = cidx & 7;
    const int row = (tile / 12) * 128 + r;
    const int col = (tile % 12) * 64 + slot * 8;
    bf16x8 o;
    if (row < 12608) {
      const float4 v0 = *(const float4*)(x + (size_t)row * 768 + col);
      const float4 v1 = *(const float4*)(x + (size_t)row * 768 + col + 4);
      o[0] = (bf16_t)v0.x; o[1] = (bf16_t)v0.y; o[2] = (bf16_t)v0.z; o[3] = (bf16_t)v0.w;
      o[4] = (bf16_t)v1.x; o[5] = (bf16_t)v1.y; o[6] = (bf16_t)v1.z; o[7] = (bf16_t)v1.w;
    } else {
      o = bf16x8{};
    }
    *(bf16x8*)(xb + (size_t)gchunk * 8) = o;
  }
}

// ---- GEMM: 128x128 block, BK=64, 256 threads (2x2 waves, 64x64/wave).
// A-operand: DIRECT global->VGPR (unswizzled tiles), double-buffered in two
//   NAMED reg sets awA/awB (static indexing; compiler manages the vmcnt for
//   the reg deps). Halves LDS traffic vs all-LDS (48 vs 96 KB per K-tile).
// B-operand: via LDS (4x reuse within block), 2x16 KB STATIC dbuf, staged
//   with global_load_lds width-16 into the proven conflict-free XOR layout.
// Handoff = round-2's PROVEN pattern: one __syncthreads per iter; its
//   implicit vmcnt(0)+lgkmcnt(0) drain retires both the B-stage and the
//   A-reg prefetch, each issued one full iteration earlier.
// launch_bounds(256,2): VGPR cap 256 (need ~180-200) -- round 3's (256,4)
//   capped at 128 and spilled everything to scratch (FETCH 535 MB, 6% MFMA).
// EPI==0: hb tiles (blocked UNSWIZZLED bf16) = gelu(gamma*acc+bias), via LDS
// EPI==1: fp32 row-major out (stride aux), rows < Mvalid
template <int EPI>
__global__ __launch_bounds__(256, 2)
void gemm_ar(const bf16_t* __restrict__ A, const bf16_t* __restrict__ B,
             const float* __restrict__ bias, const double* __restrict__ gptr,
             void* __restrict__ Cout, int nkt, int gx, int Mvalid, int aux) {
  __shared__ bf16_t sm[2][8192];       // B double buffer, 32 KB total

  // bijective XCD-chunked tile id (grid % 8 == 0 for both launches)
  const int G = gridDim.x;
  const int f = blockIdx.x;
  const int xcd = f & 7;
  const int idx = f >> 3;
  const int q8 = G >> 3, r8 = G & 7;
  const int t = xcd * q8 + (xcd < r8 ? xcd : r8) + idx;
  const int bx = t % gx;
  const int by = t / gx;

  const int tid = threadIdx.x;
  const int lane = tid & 63;
  const int wave = tid >> 6;
  const int row16 = lane & 15;
  const int quad = lane >> 4;
  const int wr = (wave >> 1) * 64;
  const int wc = (wave & 1) * 64;

  const bf16_t* const Ab = A + (size_t)by * nkt * 8192;
  const bf16_t* const Bb = B + (size_t)bx * nkt * 8192;

  // A per-lane element offset within a tile (unswizzled): row*64 + quad*8
  const int abase = (wr + row16) * 64 + quad * 8;     // +i*1024 rows, +32 ksub1
  // B swizzled LDS read offsets (proven conflict-free)
  const int sw0 = (quad ^ (row16 & 7)) * 8;
  const int boffA = (wc + row16) * 64 + sw0;          // ksub0, +j*1024
  const int boffB = (wc + row16) * 64 + (sw0 ^ 32);   // ksub1

  f32x4 acc[4][4] = {};
  bf16x8 awA[8], awB[8], bw[8];

#define LOADA_(dst, tt) do { \
    const bf16_t* ap_ = Ab + (size_t)(tt) * 8192 + abase; \
    _Pragma("unroll") for (int i_ = 0; i_ < 4; i_++) { \
      dst[2 * i_]     = *(const bf16x8*)(ap_ + i_ * 1024); \
      dst[2 * i_ + 1] = *(const bf16x8*)(ap_ + i_ * 1024 + 32); } } while (0)
#define STAGEB_(tt, bufv) do { \
    const bf16_t* sp_ = Bb + (size_t)(tt) * 8192; \
    bf16_t* dp_ = sm[bufv]; \
    _Pragma("unroll") for (int l_ = 0; l_ < 4; l_++) \
      gload_lds16(sp_ + l_ * 2048 + tid * 8, dp_ + l_ * 2048 + wave * 512); } while (0)
#define LOADB_(bufv) do { \
    const bf16_t* b0_ = sm[bufv] + boffA; \
    const bf16_t* b1_ = sm[bufv] + boffB; \
    _Pragma("unroll") for (int j_ = 0; j_ < 4; j_++) { \
      bw[2 * j_]     = *(const bf16x8*)(b0_ + j_ * 1024); \
      bw[2 * j_ + 1] = *(const bf16x8*)(b1_ + j_ * 1024); } } while (0)
#define MFMAALL_(awc) do { \
    _Pragma("unroll") for (int i_ = 0; i_ < 4; i_++) \
    _Pragma("unroll") for (int j_ = 0; j_ < 4; j_++) { \
      acc[i_][j_] = __builtin_amdgcn_mfma_f32_16x16x32_bf16(awc[2*i_],   bw[2*j_],   acc[i_][j_], 0, 0, 0); \
      acc[i_][j_] = __builtin_amdgcn_mfma_f32_16x16x32_bf16(awc[2*i_+1], bw[2*j_+1], acc[i_][j_], 0, 0, 0); } } while (0)
// Body t: compute from buf curb + regs awc; prefetch B(t+1)->buf^1 (LDS) and
// A(t+1)->awn (regs). The single __syncthreads drains both prefetches (they
// were issued a full iteration before first use) and retires curb's reads so
// next iter may overwrite it. Exactly round-2's proven handoff.
#define BODY_(tt, curb, awc, awn) do { \
    if ((tt) + 1 < nkt) { STAGEB_((tt) + 1, (curb) ^ 1); LOADA_(awn, (tt) + 1); } \
    LOADB_(curb); \
    MFMAALL_(awc); \
    __syncthreads(); } while (0)

  // prologue: stage B(0) -> buf0, load A(0) -> awA
  STAGEB_(0, 0);
  LOADA_(awA, 0);
  __syncthreads();

  for (int T = 0; T < nkt; T += 2) {   // nkt even (12 / 48)
    BODY_(T, 0, awA, awB);
    BODY_(T + 1, 1, awB, awA);
  }

  const float gamma = (float)gptr[0];
  float bv[4];
#pragma unroll
  for (int j = 0; j < 4; j++) bv[j] = bias[bx * 128 + wc + j * 16 + row16];

  if constexpr (EPI == 0) {
    // h = gelu(gamma*acc + bias) -> blocked UNSWIZZLED 128x64 tiles.
    // LDS bounce in 2 half-passes (rows {0-31,64-95} then {32-63,96-127})
    // since only 32 KB static LDS is available. SEW=136 keeps b128 aligned.
    constexpr int SEW = 136;
    bf16_t* sE = &sm[0][0];
    bf16_t* hbp = (bf16_t*)Cout;       // aux = k-tiles of h (48)
#pragma unroll
    for (int h = 0; h < 2; h++) {
#pragma unroll
      for (int u = 0; u < 2; u++) {
        const int i = 2 * h + u;
        const int rb = wr + i * 16 + quad * 4;
#pragma unroll
        for (int j = 0; j < 4; j++) {
          const int col = wc + j * 16 + row16;
#pragma unroll
          for (int r = 0; r < 4; r++) {
            const int row = rb + r;
            const int e = (row & 31) + ((row & 64) >> 1);
            sE[e * SEW + col] = (bf16_t)gelu_exact(__builtin_fmaf(gamma, acc[i][j][r], bv[j]));
          }
        }
      }
      __syncthreads();
#pragma unroll
      for (int n = 0; n < 4; n++) {
        const int g = n * 256 + tid;
        const int e = g >> 4, ch = g & 15;
        const int grow = (e & 31) + ((e & 32) << 1) + 32 * h;
        const size_t off = ((size_t)by * aux + bx * 2 + (ch >> 3)) * 8192 + (grow * 8 + (ch & 7)) * 8;
        *(bf16x8*)(hbp + off) = *(const bf16x8*)(sE + e * SEW + ch * 8);
      }
      __syncthreads();
    }
  } else {
    float* outp = (float*)Cout;        // aux = row stride (=768)
#pragma unroll
    for (int j = 0; j < 4; j++) {
      const int col = bx * 128 + wc + j * 16 + row16;
#pragma unroll
      for (int i = 0; i < 4; i++) {
        const int rb = by * 128 + wr + i * 16 + quad * 4;
#pragma unroll
        for (int r = 0; r < 4; r++)
          if (rb + r < Mvalid)
            outp[(size_t)(rb + r) * aux + col] = __builtin_fmaf(gamma, acc[i][j][r], bv[j]);
      }
    }
  }
#undef LOADA_
#undef STAGEB_
#undef LOADB_
#undef MFMAALL_
#undef BODY_
}

extern "C" void kernel_launch(void* const* d_in, const int* in_sizes, int n_in,
                              void* d_out, int out_size, void* d_ws, size_t ws_size,
                              hipStream_t stream) {
  const float* x  = (const float*)d_in[0];
  const float* w1 = (const float*)d_in[1];
  const float* b1 = (const float*)d_in[2];
  const float* w2 = (const float*)d_in[3];
  const float* b2 = (const float*)d_in[4];
  float* out = (float*)d_out;

  const int M = 64 * 197;      // 12608
  const int Mpad = 12800;      // 100 row-tiles of 128
  const int D = 768, H = 3072;
  const int nW = H * D;        // 2359296

  char* ws = (char*)d_ws;
  double* part = (double*)ws;                      // [512] @ ws[0,4096)
  double* gammas = (double*)(ws + 4096);           // [2] own cacheline
  bf16_t* xb  = (bf16_t*)(ws + 4096 + 256);        // 100x12 tiles of 128x64
  bf16_t* w1q = xb + (size_t)Mpad * D;             // 24x12 tiles
  bf16_t* w2q = w1q + (size_t)H * D;               // 6x48 tiles
  bf16_t* hb  = w2q + (size_t)D * H;               // 100x48 tiles

  reduce_part_kernel<<<512, 256, 0, stream>>>(w1, w2, nW, part);
  prep_kernel<<<2304 + 4800, 256, 0, stream>>>(w1, w2, x, part, gammas, w1q, w2q, xb);

  // GEMM1: 128x128 blocks, grid 100*24=2400; A=xb(nkt=12), B=w1q -> hb
  gemm_ar<0><<<100 * 24, 256, 0, stream>>>(xb, w1q, b1, gammas + 0, hb, 12, 24, M, H / 64);
  // GEMM2: 128x128 blocks, grid 100*6=600; A=hb(nkt=48), B=w2q -> fp32 out
  gemm_ar<1><<<100 * 6, 256, 0, stream>>>(hb, w2q, b2, gammas + 1, out, 48, 6, M, D);
}

// Round 6
// 253.094 us; speedup vs baseline: 3.3720x; 1.6990x over previous
//
#include <hip/hip_runtime.h>
#include <hip/hip_bf16.h>
#include <math.h>

typedef __bf16 bf16_t;
typedef __bf16 bf16x8 __attribute__((ext_vector_type(8)));
typedef float f32x4 __attribute__((ext_vector_type(4)));

#define QEPS 1e-5

__device__ __forceinline__ void gload_lds16(const void* g, void* l) {
  __builtin_amdgcn_global_load_lds((const __attribute__((address_space(1))) void*)g,
                                   (__attribute__((address_space(3))) void*)l, 16, 0, 0);
}

// exact GELU via A&S 7.1.26 erf (|err| <= 1.5e-7), branchless
__device__ __forceinline__ float gelu_exact(float x) {
  float a = x * 0.7071067811865476f;
  float s = fabsf(a);
  float t = __builtin_amdgcn_rcpf(__builtin_fmaf(0.3275911f, s, 1.0f));
  float p = __builtin_fmaf(1.061405429f, t, -1.453152027f);
  p = __builtin_fmaf(p, t, 1.421413741f);
  p = __builtin_fmaf(p, t, -0.284496736f);
  p = __builtin_fmaf(p, t, 0.254829592f);
  p = p * t;
  float e = __expf(-s * s);
  float er = copysignf(__builtin_fmaf(-p, e, 1.0f), a);
  return 0.5f * x * (1.0f + er);
}

// ---- P1: per-block fp64 partial sums of |w| ----
__global__ void reduce_part_kernel(const float* __restrict__ w1, const float* __restrict__ w2,
                                   int n, double* __restrict__ part) {
  const bool second = blockIdx.x >= 256;
  const float* __restrict__ w = second ? w2 : w1;
  const int b = second ? blockIdx.x - 256 : blockIdx.x;
  double s = 0.0;
  const int stride = 256 * 256 * 4;
  for (int i = (b * 256 + threadIdx.x) * 4; i < n; i += stride) {
    float4 v = *(const float4*)(w + i);
    s += (double)fabsf(v.x) + (double)fabsf(v.y) + (double)fabsf(v.z) + (double)fabsf(v.w);
  }
  for (int off = 32; off > 0; off >>= 1)
    s += __shfl_down(s, off, 64);
  __shared__ double ls[4];
  int lane = threadIdx.x & 63, wv = threadIdx.x >> 6;
  if (lane == 0) ls[wv] = s;
  __syncthreads();
  if (threadIdx.x == 0) part[blockIdx.x] = ls[0] + ls[1] + ls[2] + ls[3];
}

// ---- P2: quantize w1,w2 + cast/pad x into BLOCKED+SWIZZLED 128x32 tiles ----
// (round-0's PROVEN format/code.) Tile = 128 rows x 32 k-cols bf16 (4096
// elems, 8 KB). Chunk (r*4 + slot) holds row r, k-chunk (slot ^ (r&3)) --
// the exact image linear global_load_lds staging produces; GEMM frag reads
// at chunk quad^(row&3) alias only 2-way (measured-free, m136).
__global__ void prep_kernel(const float* __restrict__ w1, const float* __restrict__ w2,
                            const float* __restrict__ x, const double* __restrict__ part,
                            double* __restrict__ gammas, bf16_t* __restrict__ q1,
                            bf16_t* __restrict__ q2, bf16_t* __restrict__ xb) {
  const int tid = threadIdx.x;
  const int b = blockIdx.x;
  if (b < 2304) {                      // weight quantize: 1152 blocks each
    const bool second = b >= 1152;
    double p = part[(second ? 256 : 0) + tid];
    for (int off = 32; off > 0; off >>= 1)
      p += __shfl_down(p, off, 64);
    __shared__ double red[4];
    if ((tid & 63) == 0) red[tid >> 6] = p;
    __syncthreads();
    const double g = (red[0] + red[1] + red[2] + red[3]) / 2359296.0 + QEPS;
    if (tid == 0 && (b == 0 || b == 1152)) gammas[second ? 1 : 0] = g;
    const double rg = 1.0 / g;
    const int gchunk = (second ? b - 1152 : b) * 256 + tid;
    const int tile = gchunk >> 9, cidx = gchunk & 511;
    const int r = cidx >> 2, slot = cidx & 3, cch = slot ^ (r & 3);
    int row, colbase, C;
    if (second) { C = 3072; row = (tile / 96) * 128 + r; colbase = (tile % 96) * 32 + cch * 8; }
    else        { C = 768;  row = (tile / 24) * 128 + r; colbase = (tile % 24) * 32 + cch * 8; }
    const float* __restrict__ W = second ? w2 : w1;
    const float4 v0 = *(const float4*)(W + (size_t)row * C + colbase);
    const float4 v1 = *(const float4*)(W + (size_t)row * C + colbase + 4);
    bf16x8 o;
    o[0] = (bf16_t)(float)fmin(1.0, fmax(-1.0, rint((double)v0.x * rg)));
    o[1] = (bf16_t)(float)fmin(1.0, fmax(-1.0, rint((double)v0.y * rg)));
    o[2] = (bf16_t)(float)fmin(1.0, fmax(-1.0, rint((double)v0.z * rg)));
    o[3] = (bf16_t)(float)fmin(1.0, fmax(-1.0, rint((double)v0.w * rg)));
    o[4] = (bf16_t)(float)fmin(1.0, fmax(-1.0, rint((double)v1.x * rg)));
    o[5] = (bf16_t)(float)fmin(1.0, fmax(-1.0, rint((double)v1.y * rg)));
    o[6] = (bf16_t)(float)fmin(1.0, fmax(-1.0, rint((double)v1.z * rg)));
    o[7] = (bf16_t)(float)fmin(1.0, fmax(-1.0, rint((double)v1.w * rg)));
    *(bf16x8*)((second ? q2 : q1) + (size_t)gchunk * 8) = o;
  } else {                             // x cast/pad: 4752 blocks
    const int gchunk = (b - 2304) * 256 + tid;
    const int tile = gchunk >> 9, cidx = gchunk & 511;
    const int r = cidx >> 2, slot = cidx & 3, cch = slot ^ (r & 3);
    const int row = (tile / 24) * 128 + r;
    const int colbase = (tile % 24) * 32 + cch * 8;
    bf16x8 o;
    if (row < 12608) {
      const float4 v0 = *(const float4*)(x + (size_t)row * 768 + colbase);
      const float4 v1 = *(const float4*)(x + (size_t)row * 768 + colbase + 4);
      o[0] = (bf16_t)v0.x; o[1] = (bf16_t)v0.y; o[2] = (bf16_t)v0.z; o[3] = (bf16_t)v0.w;
      o[4] = (bf16_t)v1.x; o[5] = (bf16_t)v1.y; o[6] = (bf16_t)v1.z; o[7] = (bf16_t)v1.w;
    } else {
      o = bf16x8{};
    }
    *(bf16x8*)(xb + (size_t)gchunk * 8) = o;
  }
}

// ---- GEMM: 128x128 block, BK=32, 256 threads (2x2 waves, 64x64/wave).
// TRIPLE-buffered LDS (3 x {A 8KB + B 8KB} = 48 KB), stage depth 2, COUNTED
// vmcnt (T3+T4): iter T stages tile T+2 (4 gload_lds/wave), then
// s_waitcnt vmcnt(4) retires tile T+1's stage (issued a full iteration
// earlier -> latency covered), then s_barrier. The barrier never drains the
// just-issued loads.
// ROUND-5 RACE FIX: raw s_barrier is IntrNoMem to LLVM -- the scheduler may
// hoist ds_reads across it (rule-#18 family). With this schedule's 1-barrier
// read-after-stage margin, a hoisted ds_read of tile T executes after MY
// wave's vmcnt (my stage portion retired) but before OTHER waves' vmcnt ->
// stale rows (round-5: absmax 0.23). Fix: sched_barrier(0) pins on BOTH
// sides of every raw barrier -- source ledger == machine ledger, 0 runtime
// cost.
// Ledger (per wave, FIFO retirement per m135): at iter T's wait,
// outstanding = stage(T+1)[4 oldest] + stage(T+2)[4 newest]; vmcnt(4)
// retires stage(T+1). WAR: stage at iter t overwrites buf((t+2)%3), last
// read at iter t-1, whose ds_reads completed (consumed by MFMA) before that
// iter's pinned barrier. Tail: vmcnt(0) at T=nkt-2 only. nkt%3==0 (24/96).
// EPI==0: hb tiles (blocked+swizzled bf16) = gelu(gamma*acc + bias), via LDS
// EPI==1: fp32 row-major out (stride aux), rows < Mvalid
template <int EPI>
__global__ __launch_bounds__(256, 3)
void gemm_t3(const bf16_t* __restrict__ A, const bf16_t* __restrict__ B,
             const float* __restrict__ bias, const double* __restrict__ gptr,
             void* __restrict__ Cout, int nkt, int gx, int Mvalid, int aux) {
  __shared__ bf16_t sm[24576];         // [0,12288): A[3][4096]; [12288,): B[3][4096]
  bf16_t* const sA = sm;
  bf16_t* const sB = sm + 12288;

  // bijective XCD-chunked tile id
  const int G = gridDim.x;
  const int f = blockIdx.x;
  const int xcd = f & 7;
  const int idx = f >> 3;
  const int q8 = G >> 3, r8 = G & 7;
  const int t = xcd * q8 + (xcd < r8 ? xcd : r8) + idx;
  const int bx = t % gx;
  const int by = t / gx;

  const int tid = threadIdx.x;
  const int lane = tid & 63;
  const int wave = tid >> 6;
  const int row16 = lane & 15;
  const int quad = lane >> 4;
  const int wr = (wave >> 1) * 64;
  const int wc = (wave & 1) * 64;
  const int sw = (quad ^ (row16 & 3)) * 8;

  const bf16_t* const gA = A + (size_t)by * nkt * 4096;
  const bf16_t* const gB = B + (size_t)bx * nkt * 4096;
  const int o8 = tid * 8;
  const int w512 = wave * 512;

  f32x4 acc[4][4] = {};

#define STG_(T, buf) do { \
    const bf16_t* sa_ = gA + (size_t)(T) * 4096; \
    const bf16_t* sb_ = gB + (size_t)(T) * 4096; \
    gload_lds16(sa_ + o8,        sA + (buf) * 4096 + w512); \
    gload_lds16(sa_ + 2048 + o8, sA + (buf) * 4096 + 2048 + w512); \
    gload_lds16(sb_ + o8,        sB + (buf) * 4096 + w512); \
    gload_lds16(sb_ + 2048 + o8, sB + (buf) * 4096 + 2048 + w512); } while (0)
#define CMP_(buf) do { \
    const bf16_t* a_ = sA + (buf) * 4096; \
    const bf16_t* b_ = sB + (buf) * 4096; \
    bf16x8 afr[4], bfr[4]; \
    _Pragma("unroll") for (int i_ = 0; i_ < 4; i_++) \
      afr[i_] = *(const bf16x8*)&a_[(wr + i_ * 16 + row16) * 32 + sw]; \
    _Pragma("unroll") for (int j_ = 0; j_ < 4; j_++) \
      bfr[j_] = *(const bf16x8*)&b_[(wc + j_ * 16 + row16) * 32 + sw]; \
    _Pragma("unroll") for (int i_ = 0; i_ < 4; i_++) \
    _Pragma("unroll") for (int j_ = 0; j_ < 4; j_++) \
      acc[i_][j_] = __builtin_amdgcn_mfma_f32_16x16x32_bf16(afr[i_], bfr[j_], acc[i_][j_], 0, 0, 0); \
    } while (0)
#define WB4_ do { asm volatile("s_waitcnt vmcnt(4)" ::: "memory"); \
                  __builtin_amdgcn_sched_barrier(0); \
                  __builtin_amdgcn_s_barrier(); \
                  __builtin_amdgcn_sched_barrier(0); } while (0)
#define WB0_ do { asm volatile("s_waitcnt vmcnt(0)" ::: "memory"); \
                  __builtin_amdgcn_sched_barrier(0); \
                  __builtin_amdgcn_s_barrier(); \
                  __builtin_amdgcn_sched_barrier(0); } while (0)

  // prologue: stage tiles 0,1 into bufs 0,1; wait tile0 only (4 left in flight)
  STG_(0, 0);
  STG_(1, 1);
  WB4_;

  // main loop: every iter stages T+2, waits T+1
  for (int T = 0; T < nkt - 3; T += 3) {
    STG_(T + 2, 2); CMP_(0); WB4_;
    STG_(T + 3, 0); CMP_(1); WB4_;
    STG_(T + 4, 1); CMP_(2); WB4_;
  }
  // epilogue triplet: tiles nkt-3, nkt-2, nkt-1
  STG_(nkt - 1, 2); CMP_(0); WB4_;
  CMP_(1); WB0_;
  CMP_(2);

  const float gamma = (float)gptr[0];
  float bv[4];
#pragma unroll
  for (int j = 0; j < 4; j++) bv[j] = bias[bx * 128 + wc + j * 16 + row16];

  if constexpr (EPI == 0) {
    // h = gelu(gamma*acc + bias) -> blocked+swizzled 128x32 tiles via LDS.
    // 128 x SEW staging (SEW=136 keeps b128 readback 16B-aligned).
    constexpr int SEW = 136;
    bf16_t* sE = sm;                   // 128*136 = 17408 <= 24576 elems
    bf16_t* hbp = (bf16_t*)Cout;       // aux = k-tiles of h (H/32 = 96)
    __syncthreads();                   // all waves done with K-loop LDS
#pragma unroll
    for (int i = 0; i < 4; i++) {
      const int rb = wr + i * 16 + quad * 4;
#pragma unroll
      for (int j = 0; j < 4; j++) {
        const int col = wc + j * 16 + row16;
#pragma unroll
        for (int r = 0; r < 4; r++)
          sE[(rb + r) * SEW + col] =
              (bf16_t)gelu_exact(__builtin_fmaf(gamma, acc[i][j][r], bv[j]));
      }
    }
    __syncthreads();
#pragma unroll
    for (int n = 0; n < 8; n++) {      // 2048 chunks of 8 elems
      const int gc = n * 256 + tid;
      const int r = gc >> 4, c = gc & 15;
      const int kt_o = bx * 4 + (c >> 2);
      const int slot = (c & 3) ^ (r & 3);
      *(bf16x8*)&hbp[((size_t)(by * aux + kt_o)) * 4096 + r * 32 + slot * 8] =
          *(const bf16x8*)&sE[r * SEW + c * 8];
    }
  } else {
    float* outp = (float*)Cout;        // aux = row stride (=768)
#pragma unroll
    for (int j = 0; j < 4; j++) {
      const int col = bx * 128 + wc + j * 16 + row16;
#pragma unroll
      for (int i = 0; i < 4; i++) {
        const int rb = by * 128 + wr + i * 16 + quad * 4;
#pragma unroll
        for (int r = 0; r < 4; r++)
          if (rb + r < Mvalid)
            outp[(size_t)(rb + r) * aux + col] = __builtin_fmaf(gamma, acc[i][j][r], bv[j]);
      }
    }
  }
#undef STG_
#undef CMP_
#undef WB4_
#undef WB0_
}

extern "C" void kernel_launch(void* const* d_in, const int* in_sizes, int n_in,
                              void* d_out, int out_size, void* d_ws, size_t ws_size,
                              hipStream_t stream) {
  const float* x  = (const float*)d_in[0];
  const float* w1 = (const float*)d_in[1];
  const float* b1 = (const float*)d_in[2];
  const float* w2 = (const float*)d_in[3];
  const float* b2 = (const float*)d_in[4];
  float* out = (float*)d_out;

  const int M = 64 * 197;      // 12608
  const int Mpad = 12672;      // 99 * 128
  const int D = 768, H = 3072;
  const int nW = H * D;        // 2359296

  char* ws = (char*)d_ws;
  double* part = (double*)ws;                      // [512] @ ws[0,4096)
  double* gammas = (double*)(ws + 4096);           // [2] own cacheline
  bf16_t* xb  = (bf16_t*)(ws + 4096 + 256);        // 99x24 tiles of 128x32
  bf16_t* w1q = xb + (size_t)Mpad * D;             // 24x24 tiles
  bf16_t* w2q = w1q + (size_t)H * D;               // 6x96 tiles
  bf16_t* hb  = w2q + (size_t)D * H;               // 99x96 tiles

  reduce_part_kernel<<<512, 256, 0, stream>>>(w1, w2, nW, part);
  prep_kernel<<<2304 + 4752, 256, 0, stream>>>(w1, w2, x, part, gammas, w1q, w2q, xb);

  // GEMM1: 128x128 blocks, grid 99*24=2376; A=xb(nkt=24), B=w1q -> hb blocked
  gemm_t3<0><<<99 * 24, 256, 0, stream>>>(xb, w1q, b1, gammas + 0, hb, 24, 24, M, H / 32);
  // GEMM2: 128x128 blocks, grid 99*6=594; A=hb(nkt=96), B=w2q -> fp32 out
  gemm_t3<1><<<99 * 6, 256, 0, stream>>>(hb, w2q, b2, gammas + 1, out, 96, 6, M, D);
}

// Round 7
// 252.726 us; speedup vs baseline: 3.3770x; 1.0015x over previous
//
#include <hip/hip_runtime.h>
#include <hip/hip_bf16.h>
#include <math.h>

typedef __bf16 bf16_t;
typedef __bf16 bf16x8 __attribute__((ext_vector_type(8)));
typedef float f32x4 __attribute__((ext_vector_type(4)));

#define QEPS 1e-5

__device__ __forceinline__ void gload_lds16(const void* g, void* l) {
  __builtin_amdgcn_global_load_lds((const __attribute__((address_space(1))) void*)g,
                                   (__attribute__((address_space(3))) void*)l, 16, 0, 0);
}

// exact GELU via A&S 7.1.26 erf (|err| <= 1.5e-7), branchless
__device__ __forceinline__ float gelu_exact(float x) {
  float a = x * 0.7071067811865476f;
  float s = fabsf(a);
  float t = __builtin_amdgcn_rcpf(__builtin_fmaf(0.3275911f, s, 1.0f));
  float p = __builtin_fmaf(1.061405429f, t, -1.453152027f);
  p = __builtin_fmaf(p, t, 1.421413741f);
  p = __builtin_fmaf(p, t, -0.284496736f);
  p = __builtin_fmaf(p, t, 0.254829592f);
  p = p * t;
  float e = __expf(-s * s);
  float er = copysignf(__builtin_fmaf(-p, e, 1.0f), a);
  return 0.5f * x * (1.0f + er);
}

// ---- P1: per-block fp64 partial sums of |w| ----
__global__ void reduce_part_kernel(const float* __restrict__ w1, const float* __restrict__ w2,
                                   int n, double* __restrict__ part) {
  const bool second = blockIdx.x >= 256;
  const float* __restrict__ w = second ? w2 : w1;
  const int b = second ? blockIdx.x - 256 : blockIdx.x;
  double s = 0.0;
  const int stride = 256 * 256 * 4;
  for (int i = (b * 256 + threadIdx.x) * 4; i < n; i += stride) {
    float4 v = *(const float4*)(w + i);
    s += (double)fabsf(v.x) + (double)fabsf(v.y) + (double)fabsf(v.z) + (double)fabsf(v.w);
  }
  for (int off = 32; off > 0; off >>= 1)
    s += __shfl_down(s, off, 64);
  __shared__ double ls[4];
  int lane = threadIdx.x & 63, wv = threadIdx.x >> 6;
  if (lane == 0) ls[wv] = s;
  __syncthreads();
  if (threadIdx.x == 0) part[blockIdx.x] = ls[0] + ls[1] + ls[2] + ls[3];
}

// ---- P2: quantize w1,w2 + cast/pad x, all into BLOCKED+SWIZZLED layout ----
// Same per-chunk logic & output formats as the round-0 harness-verified prep
// (tile = 128 rows x 32 k-cols, chunk r*4+slot holds k-chunk slot^(r&3)),
// restructured for density: 4 chunks per thread, 1764 blocks total
// (576 weight blocks + 1188 x blocks) instead of 7056 single-chunk blocks.
// prep is launch/scheduling-bound, not BW-bound (~87 MB moved): fewer,
// fatter blocks give each thread 4 independent load->cvt->store chains.
__global__ void prep_kernel(const float* __restrict__ w1, const float* __restrict__ w2,
                            const float* __restrict__ x, const double* __restrict__ part,
                            double* __restrict__ gammas, bf16_t* __restrict__ q1,
                            bf16_t* __restrict__ q2, bf16_t* __restrict__ xb) {
  const int tid = threadIdx.x;
  const int b = blockIdx.x;
  if (b < 576) {                       // weight quantize: 288 blocks each
    const bool second = b >= 288;
    double p = part[(second ? 256 : 0) + tid];
    for (int off = 32; off > 0; off >>= 1)
      p += __shfl_down(p, off, 64);
    __shared__ double red[4];
    if ((tid & 63) == 0) red[tid >> 6] = p;
    __syncthreads();
    const double g = (red[0] + red[1] + red[2] + red[3]) / 2359296.0 + QEPS;
    if (tid == 0 && (b == 0 || b == 288)) gammas[second ? 1 : 0] = g;
    const double rg = 1.0 / g;
    const float* __restrict__ W = second ? w2 : w1;
    bf16_t* __restrict__ Q = second ? q2 : q1;
    const int base = (second ? b - 288 : b) * 1024;
#pragma unroll
    for (int c = 0; c < 4; c++) {
      const int gchunk = base + c * 256 + tid;      // < 294912
      const int tile = gchunk >> 9, cidx = gchunk & 511;
      const int r = cidx >> 2, slot = cidx & 3, cch = slot ^ (r & 3);
      int row, colbase, C;
      if (second) { C = 3072; row = (tile / 96) * 128 + r; colbase = (tile % 96) * 32 + cch * 8; }
      else        { C = 768;  row = (tile / 24) * 128 + r; colbase = (tile % 24) * 32 + cch * 8; }
      const float4 v0 = *(const float4*)(W + (size_t)row * C + colbase);
      const float4 v1 = *(const float4*)(W + (size_t)row * C + colbase + 4);
      bf16x8 o;
      o[0] = (bf16_t)(float)fmin(1.0, fmax(-1.0, rint((double)v0.x * rg)));
      o[1] = (bf16_t)(float)fmin(1.0, fmax(-1.0, rint((double)v0.y * rg)));
      o[2] = (bf16_t)(float)fmin(1.0, fmax(-1.0, rint((double)v0.z * rg)));
      o[3] = (bf16_t)(float)fmin(1.0, fmax(-1.0, rint((double)v0.w * rg)));
      o[4] = (bf16_t)(float)fmin(1.0, fmax(-1.0, rint((double)v1.x * rg)));
      o[5] = (bf16_t)(float)fmin(1.0, fmax(-1.0, rint((double)v1.y * rg)));
      o[6] = (bf16_t)(float)fmin(1.0, fmax(-1.0, rint((double)v1.z * rg)));
      o[7] = (bf16_t)(float)fmin(1.0, fmax(-1.0, rint((double)v1.w * rg)));
      *(bf16x8*)(Q + (size_t)gchunk * 8) = o;
    }
  } else {                             // x cast/pad: 1188 blocks x 1024 chunks
    const int base = (b - 576) * 1024;
#pragma unroll
    for (int c = 0; c < 4; c++) {
      const int gchunk = base + c * 256 + tid;      // < 1216512
      const int tile = gchunk >> 9, cidx = gchunk & 511;
      const int r = cidx >> 2, slot = cidx & 3, cch = slot ^ (r & 3);
      const int row = (tile / 24) * 128 + r;
      const int colbase = (tile % 24) * 32 + cch * 8;
      bf16x8 o;
      if (row < 12608) {
        const float4 v0 = *(const float4*)(x + (size_t)row * 768 + colbase);
        const float4 v1 = *(const float4*)(x + (size_t)row * 768 + colbase + 4);
        o[0] = (bf16_t)v0.x; o[1] = (bf16_t)v0.y; o[2] = (bf16_t)v0.z; o[3] = (bf16_t)v0.w;
        o[4] = (bf16_t)v1.x; o[5] = (bf16_t)v1.y; o[6] = (bf16_t)v1.z; o[7] = (bf16_t)v1.w;
      } else {
        o = bf16x8{};
      }
      *(bf16x8*)(xb + (size_t)gchunk * 8) = o;
    }
  }
}

// ---- GEMM: C = A(128-row tiles) x B(128-row tiles)^T over blocked operands ----
// ROUND-0 HARNESS-PROVEN KERNEL, VERBATIM (86 / 85.6 us). Block tile 128 x BN
// (BN = NJ*32), BK=32, LDS double-buffered, ONE barrier per iter; prefetch of
// tile kt+1 issues before compute of kt so the barrier's vmcnt(0) drain is
// covered by the MFMA phase. Wave tile 64 x (BN/2). Rounds 1-6 established
// that every alternative schedule (8-phase 256^2, BK=64 dbuf, reg-A prefetch,
// triple-buffer counted-vmcnt) is equal or worse at these shapes.
// EPI==0: h tiles (blocked+swizzled bf16) = gelu(gamma*acc + bias)
// EPI==1: fp32 row-major out (stride aux), rows < Mvalid
template <int EPI, int NJ>
__global__ __launch_bounds__(256, (NJ == 8 ? 2 : 3))
void gemm_tiled(const bf16_t* __restrict__ A, const bf16_t* __restrict__ B,
                const float* __restrict__ bias, const double* __restrict__ gptr,
                void* __restrict__ Cout, int nkt, int gx, int Mvalid, int aux) {
  constexpr int BN = NJ * 32;
  constexpr int BTILE = BN * 32;           // B block-tile elems per k-slice
  constexpr int NRTB = BN / 128;           // 128-row tiles per B block-tile
  __shared__ bf16_t sm[2 * 4096 + 2 * BTILE];
  bf16_t* const sA0 = sm;                   // [2][4096]
  bf16_t* const sB0 = sm + 2 * 4096;        // [2][BTILE]

  // XCD-chunked tile id (block f -> XCD f%8, contiguous chunk per XCD)
  const int G = gridDim.x;
  const int f = blockIdx.x;
  const int xcd = f & 7;
  const int idx = f >> 3;
  const int q8 = G >> 3, r8 = G & 7;
  const int t = xcd * q8 + (xcd < r8 ? xcd : r8) + idx;
  const int bx = t % gx;
  const int by = t / gx;

  const int tid = threadIdx.x;
  const int lane = tid & 63;
  const int wave = tid >> 6;               // 2x2 wave grid
  const int wr = (wave >> 1) * 64;
  const int wc = (wave & 1) * (BN / 2);
  const int row16 = lane & 15;
  const int quad = lane >> 4;

  const bf16_t* gA = A + ((size_t)by * nkt) * 4096 + tid * 8;
  const bf16_t* gB0 = B + ((size_t)(bx * NRTB) * nkt) * 4096 + tid * 8;
  const bf16_t* gB1 = (NJ == 8) ? B + ((size_t)(bx * NRTB + 1) * nkt) * 4096 + tid * 8 : nullptr;
  const int lws = wave * 512;              // wave-uniform; builtin adds lane*16B

  f32x4 acc[4][NJ] = {};

  // stage tile 0 into buf 0
  {
    gload_lds16(gA, sA0 + lws);
    gload_lds16(gA + 2048, sA0 + 2048 + lws);
    gload_lds16(gB0, sB0 + lws);
    gload_lds16(gB0 + 2048, sB0 + 2048 + lws);
    if constexpr (NJ == 8) {
      gload_lds16(gB1, sB0 + 4096 + lws);
      gload_lds16(gB1 + 2048, sB0 + 6144 + lws);
    }
    gA += 4096; gB0 += 4096;
    if constexpr (NJ == 8) gB1 += 4096;
  }
  __syncthreads();

  int p = 0;
  const int sw = (quad ^ (row16 & 3)) * 8;
  for (int kt = 0; kt < nkt; kt++) {
    if (kt + 1 < nkt) {                    // prefetch next tile into buf p^1
      bf16_t* dA = sA0 + (p ^ 1) * 4096;
      bf16_t* dB = sB0 + (p ^ 1) * BTILE;
      gload_lds16(gA, dA + lws);
      gload_lds16(gA + 2048, dA + 2048 + lws);
      gload_lds16(gB0, dB + lws);
      gload_lds16(gB0 + 2048, dB + 2048 + lws);
      if constexpr (NJ == 8) {
        gload_lds16(gB1, dB + 4096 + lws);
        gload_lds16(gB1 + 2048, dB + 6144 + lws);
      }
      gA += 4096; gB0 += 4096;
      if constexpr (NJ == 8) gB1 += 4096;
    }
    const bf16_t* sA = sA0 + p * 4096;
    const bf16_t* sB = sB0 + p * BTILE;
    bf16x8 afr[4], bfr[NJ];
#pragma unroll
    for (int i = 0; i < 4; i++)
      afr[i] = *(const bf16x8*)&sA[(wr + i * 16 + row16) * 32 + sw];
#pragma unroll
    for (int j = 0; j < NJ; j++)
      bfr[j] = *(const bf16x8*)&sB[(wc + j * 16 + row16) * 32 + sw];
#pragma unroll
    for (int i = 0; i < 4; i++)
#pragma unroll
      for (int j = 0; j < NJ; j++)
        acc[i][j] = __builtin_amdgcn_mfma_f32_16x16x32_bf16(afr[i], bfr[j], acc[i][j], 0, 0, 0);
    __syncthreads();                       // readers done with p; p^1 loads drained
    p ^= 1;
  }

  const float gamma = (float)gptr[0];

  if constexpr (EPI == 0) {
    // write h in blocked+swizzled tile layout; aux = total k-tiles of h (H/32)
    constexpr int SEW = BN + 8;
    bf16_t* sE = sm;                       // 32*SEW <= sm size
    bf16_t* h = (bf16_t*)Cout;
    float bv[NJ];
#pragma unroll
    for (int j = 0; j < NJ; j++) bv[j] = bias[bx * BN + wc + row16 + j * 16];
    const int ktBase = bx * (BN / 32);
#pragma unroll
    for (int i = 0; i < 4; i++) {
#pragma unroll
      for (int j = 0; j < NJ; j++) {
        const int col = wc + j * 16 + row16;
#pragma unroll
        for (int r = 0; r < 4; r++) {
          const int e = (wave >> 1) * 16 + quad * 4 + r;
          sE[e * SEW + col] = (bf16_t)gelu_exact(gamma * acc[i][j][r] + bv[j]);
        }
      }
      __syncthreads();
      {
        const int e2 = tid >> 3, chb = tid & 7;
        const int r_in = (e2 >> 4) * 64 + i * 16 + (e2 & 15);
#pragma unroll
        for (int cc = 0; cc < BN / 64; cc++) {
          const int c = chb + cc * 8;
          const int kt_o = ktBase + (c >> 2);
          const int slot = (c & 3) ^ (r_in & 3);
          const size_t off = ((size_t)(by * aux + kt_o)) * 4096 + r_in * 32 + slot * 8;
          *(bf16x8*)&h[off] = *(const bf16x8*)&sE[e2 * SEW + c * 8];
        }
      }
      __syncthreads();
    }
  } else {
    float* out = (float*)Cout;             // aux = row stride (=768)
    const int c_base = bx * BN + wc + row16;
    const int r_base = by * 128 + wr + quad * 4;
#pragma unroll
    for (int j = 0; j < NJ; j++) {
      const int col = c_base + j * 16;
      const float bv = bias[col];
#pragma unroll
      for (int i = 0; i < 4; i++) {
#pragma unroll
        for (int r = 0; r < 4; r++) {
          const int row = r_base + i * 16 + r;
          if (row < Mvalid)
            out[(size_t)row * aux + col] = gamma * acc[i][j][r] + bv;
        }
      }
    }
  }
}

extern "C" void kernel_launch(void* const* d_in, const int* in_sizes, int n_in,
                              void* d_out, int out_size, void* d_ws, size_t ws_size,
                              hipStream_t stream) {
  const float* x  = (const float*)d_in[0];
  const float* w1 = (const float*)d_in[1];
  const float* b1 = (const float*)d_in[2];
  const float* w2 = (const float*)d_in[3];
  const float* b2 = (const float*)d_in[4];
  float* out = (float*)d_out;

  const int M = 64 * 197;      // 12608
  const int Mpad = 12672;      // 99 * 128
  const int D = 768, H = 3072;
  const int nW = H * D;        // 2359296

  char* ws = (char*)d_ws;
  double* part = (double*)ws;                      // [512] @ ws[0,4096)
  double* gammas = (double*)(ws + 4096);           // [2] own cacheline
  bf16_t* xb  = (bf16_t*)(ws + 4096 + 256);        // 99x24 tiles
  bf16_t* w1q = xb + (size_t)Mpad * D;             // 24x24 tiles
  bf16_t* w2q = w1q + (size_t)H * D;               // 6x96 tiles
  bf16_t* hb  = w2q + (size_t)D * H;               // 99x96 tiles

  reduce_part_kernel<<<512, 256, 0, stream>>>(w1, w2, nW, part);
  prep_kernel<<<1764, 256, 0, stream>>>(w1, w2, x, part, gammas, w1q, w2q, xb);

  // GEMM1: 128x256 blocks, grid 99*12; A=xb(nkt=24), B=w1q -> hb blocked
  gemm_tiled<0, 8><<<99 * 12, 256, 0, stream>>>(xb, w1q, b1, gammas + 0, hb, 24, 12, M, H / 32);
  // GEMM2: 128x128 blocks, grid 99*6; A=hb(nkt=96), B=w2q -> fp32 out
  gemm_tiled<1, 4><<<99 * 6, 256, 0, stream>>>(hb, w2q, b2, gammas + 1, out, 96, 6, M, D);
}